// Round 9
// baseline (72.767 us; speedup 1.0000x reference)
//
#include <hip/hip_runtime.h>

// Stand-alone self-attention block, fully fused.
// x:(8,64,128,128) f32 -> out same shape. G=8, Cg=8, 3x3 window, pad 1.
//
// R9 = R8 (32x32 tile x 2-ch chunk, 4 px/thread, pk-f32 math, SGPR
// weights, streaming no-max exp2 softmax) + occupancy: target VGPR<=64
// (the 64/128 quantization cliff -> 32 waves/CU instead of 16):
//  - conv streamed in two 4-channel halves (4 xi v4f in flight, not 8)
//  - LDS stride 38->36 float2: 19.6 KB/block -> 8 blocks/CU under 160 KB
//    (bank quad = (r+c)%4 -> 2-way on b128 reads = free per m136)
//  - __launch_bounds__(256,8) forces the <=64 allocation
// Tripwire: WRITE_SIZE > 40 MB means scratch spill -> revert.

typedef float v2f __attribute__((ext_vector_type(2)));
typedef float v4f __attribute__((ext_vector_type(4)));

#define HH 128
#define WW 128
#define HW (HH * WW)
#define PT 34          // padded tile extent (32 + halo)
#define PTS 36         // row stride in float2 (34 + 2 pad; rows 16B-aligned)
#define LOG2E 1.44269504088896f

__device__ __forceinline__ float sload(float v) {
    // force block-uniform value into an SGPR
    return __uint_as_float(__builtin_amdgcn_readfirstlane(__float_as_uint(v)));
}

__device__ __forceinline__ v4f exp2v4(v4f a) {
    v4f r;
    r.x = __builtin_amdgcn_exp2f(a.x);
    r.y = __builtin_amdgcn_exp2f(a.y);
    r.z = __builtin_amdgcn_exp2f(a.z);
    r.w = __builtin_amdgcn_exp2f(a.w);
    return r;
}

__global__ __launch_bounds__(256, 8) void sab_fused(
    const float* __restrict__ x,
    const float* __restrict__ Wq,
    const float* __restrict__ Wk,
    const float* __restrict__ Wv,
    const float* __restrict__ h_emb,
    const float* __restrict__ w_emb,
    float* __restrict__ out)
{
    __shared__ v2f kv[2][PT][PTS];      // [cc][row][col] {k,v}  (19.6 KB)

    const int bid0 = blockIdx.x;
    const int work = (bid0 & 7) * 512 + (bid0 >> 3);   // bijective XCD swizzle
    const int c0   = (work & 3) << 1;          // channel chunk {0,2,4,6}
    const int tile = (work >> 2) & 15;         // 4x4 tiles of 32x32
    const int bg   = work >> 6;                // b*8 + g
    const int g    = bg & 7;
    const int h0   = (tile >> 2) << 5;
    const int w0   = (tile & 3) << 5;
    const int tid  = threadIdx.x;
    const int ty   = tid >> 3;                 // 0..31
    const int x0   = (tid & 7) << 2;           // 0,4,..,28

    // ---- weights + emb -> SGPRs (readfirstlane-forced) ----
    float wk[2][8], wv[2][8], wq[2][8], eb[2][9];
    #pragma unroll
    for (int cc = 0; cc < 2; cc++) {
        const int c = c0 + cc;
        #pragma unroll
        for (int i = 0; i < 8; i++) {
            wk[cc][i] = sload(Wk[g * 64 + c * 8 + i]);
            wv[cc][i] = sload(Wv[g * 64 + c * 8 + i]);
            wq[cc][i] = sload(Wq[g * 64 + c * 8 + i]);
        }
        #pragma unroll
        for (int p = 0; p < 9; p++) {
            // channels 0-3: h_emb (ki = p/3); 4-7: w_emb (kj = p%3)
            eb[cc][p] = sload((c < 4) ? h_emb[(g * 4 + c) * 3 + p / 3]
                                      : w_emb[(g * 4 + c - 4) * 3 + p % 3]);
        }
    }

    const float* xb = x + (size_t)bg * 8 * HW;
    const int ibase = (h0 + ty) * WW + (w0 + x0);

    // ---- conv (packed, streamed in two 4-channel halves) ----
    v4f kk0 = 0.f, vv0 = 0.f, qq0 = 0.f, kk1 = 0.f, vv1 = 0.f, qq1 = 0.f;
    #pragma unroll
    for (int ih = 0; ih < 2; ih++) {
        v4f xt[4];
        #pragma unroll
        for (int j = 0; j < 4; j++)
            xt[j] = *reinterpret_cast<const v4f*>(xb + (ih * 4 + j) * HW + ibase);
        #pragma unroll
        for (int j = 0; j < 4; j++) {
            const int i = ih * 4 + j;
            const v4f xv = xt[j];
            kk0 += wk[0][i] * xv;  vv0 += wv[0][i] * xv;  qq0 += wq[0][i] * xv;
            kk1 += wk[1][i] * xv;  vv1 += wv[1][i] * xv;  qq1 += wq[1][i] * xv;
        }
    }
    #pragma unroll
    for (int px = 0; px < 4; px++) {
        kv[0][ty + 1][x0 + 1 + px] = (v2f){kk0[px], vv0[px]};
        kv[1][ty + 1][x0 + 1 + px] = (v2f){kk1[px], vv1[px]};
    }
    const v4f q0 = qq0 * LOG2E;
    const v4f q1 = qq1 * LOG2E;

    // ---- halo: 132 perimeter px on threads 0..131 (transient state) ----
    if (tid < 132) {
        int hpy, hpx;
        if (tid < 34)       { hpy = 0;        hpx = tid; }
        else if (tid < 68)  { hpy = 33;       hpx = tid - 34; }
        else if (tid < 100) { hpy = tid - 67; hpx = 0; }     // rows 1..32
        else                { hpy = tid - 99; hpx = 33; }
        const int gh = h0 + hpy - 1, gw = w0 + hpx - 1;
        const bool ok = (gh >= 0) & (gh < HH) & (gw >= 0) & (gw < WW);
        const int base = gh * WW + gw;
        float hk0 = 0.f, hv0 = 0.f, hk1 = 0.f, hv1 = 0.f;
        #pragma unroll
        for (int i = 0; i < 8; i++) {
            const float xv = ok ? xb[i * HW + base] : 0.0f;
            hk0 = fmaf(wk[0][i], xv, hk0);
            hv0 = fmaf(wv[0][i], xv, hv0);
            hk1 = fmaf(wk[1][i], xv, hk1);
            hv1 = fmaf(wv[1][i], xv, hv1);
        }
        kv[0][hpy][hpx] = (v2f){hk0, hv0};
        kv[1][hpy][hpx] = (v2f){hk1, hv1};
    }
    __syncthreads();

    // ---- attention: streaming rows, packed 4-px softmax ----
    v4f s0 = 0.f, o0 = 0.f, s1 = 0.f, o1 = 0.f;
    #pragma unroll
    for (int dh = 0; dh < 3; dh++) {
        #pragma unroll
        for (int cc = 0; cc < 2; cc++) {
            const v2f* row = &kv[cc][ty + dh][x0];
            const v4f a = *reinterpret_cast<const v4f*>(row);       // k0 v0 k1 v1
            const v4f bq = *reinterpret_cast<const v4f*>(row + 2);  // k2 v2 k3 v3
            const v4f cq = *reinterpret_cast<const v4f*>(row + 4);  // k4 v4 k5 v5

            const v4f kd0 = {a.x, a.z, bq.x, bq.z};
            const v4f vd0 = {a.y, a.w, bq.y, bq.w};
            const v4f kd1 = {a.z, bq.x, bq.z, cq.x};
            const v4f vd1 = {a.w, bq.y, bq.w, cq.y};
            const v4f kd2 = {bq.x, bq.z, cq.x, cq.z};
            const v4f vd2 = {bq.y, bq.w, cq.y, cq.w};

            const v4f q4 = cc ? q1 : q0;
            v4f e;
            e = exp2v4(q4 * (kd0 + eb[cc][dh * 3 + 0]));
            if (cc) { s1 += e; o1 += e * vd0; } else { s0 += e; o0 += e * vd0; }
            e = exp2v4(q4 * (kd1 + eb[cc][dh * 3 + 1]));
            if (cc) { s1 += e; o1 += e * vd1; } else { s0 += e; o0 += e * vd1; }
            e = exp2v4(q4 * (kd2 + eb[cc][dh * 3 + 2]));
            if (cc) { s1 += e; o1 += e * vd2; } else { s0 += e; o0 += e * vd2; }
        }
    }

    // ---- normalize + store (dwordx4 per channel) ----
    v4f r0, r1;
    #pragma unroll
    for (int px = 0; px < 4; px++) {
        r0[px] = o0[px] * __builtin_amdgcn_rcpf(s0[px]);
        r1[px] = o1[px] * __builtin_amdgcn_rcpf(s1[px]);
    }
    *reinterpret_cast<v4f*>(out + (size_t)(bg * 8 + c0 + 0) * HW + ibase) = r0;
    *reinterpret_cast<v4f*>(out + (size_t)(bg * 8 + c0 + 1) * HW + ibase) = r1;
}

extern "C" void kernel_launch(void* const* d_in, const int* in_sizes, int n_in,
                              void* d_out, int out_size, void* d_ws, size_t ws_size,
                              hipStream_t stream) {
    const float* x    = (const float*)d_in[0];
    const float* Wq   = (const float*)d_in[1];
    const float* Wk   = (const float*)d_in[2];
    const float* Wv   = (const float*)d_in[3];
    const float* h_e  = (const float*)d_in[4];
    const float* w_e  = (const float*)d_in[5];
    float* out = (float*)d_out;

    dim3 grid(8 * 8 * 16 * 4);   // (b,g) x 4x4 tiles x 4 channel-chunks
    dim3 block(256);
    sab_fused<<<grid, block, 0, stream>>>(x, Wq, Wk, Wv, h_e, w_e, out);
}

// Round 10
// 31.109 us; speedup vs baseline: 2.3391x; 2.3391x over previous
//
#include <hip/hip_runtime.h>

// Stand-alone self-attention block, fully fused.
// x:(8,64,128,128) f32 -> out same shape. G=8, Cg=8, 3x3 window, pad 1.
//
// R10: 1 block = one (b,g) x 32x32 tile, ALL 8 channels, 4 chunk-iterations.
//  - x loaded ONCE into regs (xi[8] v4f interior, hx[8] halo) and reused by
//    all 4 chunks: 4x fewer VMEM instructions + L2 reads than R8
//  - chunk loop NOT unrolled (#pragma unroll 1): only one chunk's 66
//    weights live in SGPRs at a time (readfirstlane-forced, R7-proven)
//  - kv single buffer, stride 38 float2 (R8 layout: b128 read quad
//    (19r+2t)%8 covers all 8 -> conflict-free); 2 barriers per chunk
//  - pk-f32 math, streaming no-max exp2 softmax, v_rcp normalize
//  - NO launch_bounds forcing (R6/R9 proved it causes scratch spill)

typedef float v2f __attribute__((ext_vector_type(2)));
typedef float v4f __attribute__((ext_vector_type(4)));

#define HH 128
#define WW 128
#define HW (HH * WW)
#define PT 34          // padded tile extent (32 + halo)
#define PTS 38         // row stride in float2 (34 + 4 pad)
#define LOG2E 1.44269504088896f

__device__ __forceinline__ float sload(float v) {
    // force block-uniform value into an SGPR
    return __uint_as_float(__builtin_amdgcn_readfirstlane(__float_as_uint(v)));
}

__device__ __forceinline__ v4f exp2v4(v4f a) {
    v4f r;
    r.x = __builtin_amdgcn_exp2f(a.x);
    r.y = __builtin_amdgcn_exp2f(a.y);
    r.z = __builtin_amdgcn_exp2f(a.z);
    r.w = __builtin_amdgcn_exp2f(a.w);
    return r;
}

__global__ __launch_bounds__(256) void sab_fused(
    const float* __restrict__ x,
    const float* __restrict__ Wq,
    const float* __restrict__ Wk,
    const float* __restrict__ Wv,
    const float* __restrict__ h_emb,
    const float* __restrict__ w_emb,
    float* __restrict__ out)
{
    __shared__ v2f kv[2][PT][PTS];      // [cc][row][col] {k,v}  (20.7 KB)

    const int bid0 = blockIdx.x;
    const int work = (bid0 & 7) * 128 + (bid0 >> 3);   // bijective XCD swizzle
    const int tile = work & 15;                // 4x4 tiles of 32x32
    const int bg   = work >> 4;                // b*8 + g
    const int g    = bg & 7;
    const int h0   = (tile >> 2) << 5;
    const int w0   = (tile & 3) << 5;
    const int tid  = threadIdx.x;
    const int ty   = tid >> 3;                 // 0..31
    const int x0   = (tid & 7) << 2;           // 0,4,..,28

    const float* xb = x + (size_t)bg * 8 * HW;
    const int ibase = (h0 + ty) * WW + (w0 + x0);

    // ---- halo classification + x (persist; threads 0..131) ----
    int hpy = 0, hpx = 0;
    const bool is_halo = tid < 132;
    if (is_halo) {
        if (tid < 34)       { hpy = 0;        hpx = tid; }
        else if (tid < 68)  { hpy = 33;       hpx = tid - 34; }
        else if (tid < 100) { hpy = tid - 67; hpx = 0; }     // rows 1..32
        else                { hpy = tid - 99; hpx = 33; }
    }
    const int hgh = h0 + hpy - 1, hgw = w0 + hpx - 1;
    const bool hok = is_halo & (hgh >= 0) & (hgh < HH) & (hgw >= 0) & (hgw < WW);
    const int hbase = hgh * WW + hgw;

    float hx[8];
    #pragma unroll
    for (int i = 0; i < 8; i++)
        hx[i] = hok ? xb[i * HW + hbase] : 0.0f;

    // ---- interior x: 4 px, 8 channels (dwordx4), loaded once ----
    v4f xi[8];
    #pragma unroll
    for (int i = 0; i < 8; i++)
        xi[i] = *reinterpret_cast<const v4f*>(xb + i * HW + ibase);

    // ---- 4 chunk-iterations of 2 channels each ----
    #pragma unroll 1
    for (int chunk = 0; chunk < 4; ++chunk) {
        if (chunk) __syncthreads();            // prior attn done before overwrite
        const int c0 = chunk << 1;

        // weights + emb -> SGPRs (readfirstlane-forced), this chunk only
        float wk[2][8], wv[2][8], wq[2][8], eb[2][9];
        #pragma unroll
        for (int cc = 0; cc < 2; cc++) {
            const int c = c0 + cc;
            #pragma unroll
            for (int i = 0; i < 8; i++) {
                wk[cc][i] = sload(Wk[g * 64 + c * 8 + i]);
                wv[cc][i] = sload(Wv[g * 64 + c * 8 + i]);
                wq[cc][i] = sload(Wq[g * 64 + c * 8 + i]);
            }
            #pragma unroll
            for (int p = 0; p < 9; p++) {
                // channels 0-3: h_emb (ki = p/3); 4-7: w_emb (kj = p%3)
                eb[cc][p] = sload((c < 4) ? h_emb[(g * 4 + c) * 3 + p / 3]
                                          : w_emb[(g * 4 + c - 4) * 3 + p % 3]);
            }
        }

        // conv interior (packed): k,v -> LDS, q -> regs
        v4f kk0 = 0.f, vv0 = 0.f, qq0 = 0.f, kk1 = 0.f, vv1 = 0.f, qq1 = 0.f;
        #pragma unroll
        for (int i = 0; i < 8; i++) {
            const v4f xv = xi[i];
            kk0 += wk[0][i] * xv;  vv0 += wv[0][i] * xv;  qq0 += wq[0][i] * xv;
            kk1 += wk[1][i] * xv;  vv1 += wv[1][i] * xv;  qq1 += wq[1][i] * xv;
        }
        #pragma unroll
        for (int px = 0; px < 4; px++) {
            kv[0][ty + 1][x0 + 1 + px] = (v2f){kk0[px], vv0[px]};
            kv[1][ty + 1][x0 + 1 + px] = (v2f){kk1[px], vv1[px]};
        }
        const v4f q0 = qq0 * LOG2E;
        const v4f q1 = qq1 * LOG2E;

        // conv halo
        if (is_halo) {
            float hk0 = 0.f, hv0 = 0.f, hk1 = 0.f, hv1 = 0.f;
            #pragma unroll
            for (int i = 0; i < 8; i++) {
                hk0 = fmaf(wk[0][i], hx[i], hk0);
                hv0 = fmaf(wv[0][i], hx[i], hv0);
                hk1 = fmaf(wk[1][i], hx[i], hk1);
                hv1 = fmaf(wv[1][i], hx[i], hv1);
            }
            kv[0][hpy][hpx] = (v2f){hk0, hv0};
            kv[1][hpy][hpx] = (v2f){hk1, hv1};
        }
        __syncthreads();

        // attention: streaming rows, packed 4-px softmax
        v4f s0 = 0.f, o0 = 0.f, s1 = 0.f, o1 = 0.f;
        #pragma unroll
        for (int dh = 0; dh < 3; dh++) {
            #pragma unroll
            for (int cc = 0; cc < 2; cc++) {
                const v2f* row = &kv[cc][ty + dh][x0];
                const v4f a  = *reinterpret_cast<const v4f*>(row);      // k0 v0 k1 v1
                const v4f bq = *reinterpret_cast<const v4f*>(row + 2);  // k2 v2 k3 v3
                const v4f cq = *reinterpret_cast<const v4f*>(row + 4);  // k4 v4 k5 v5

                const v4f kd0 = {a.x, a.z, bq.x, bq.z};
                const v4f vd0 = {a.y, a.w, bq.y, bq.w};
                const v4f kd1 = {a.z, bq.x, bq.z, cq.x};
                const v4f vd1 = {a.w, bq.y, bq.w, cq.y};
                const v4f kd2 = {bq.x, bq.z, cq.x, cq.z};
                const v4f vd2 = {bq.y, bq.w, cq.y, cq.w};

                const v4f q4 = cc ? q1 : q0;
                v4f e;
                e = exp2v4(q4 * (kd0 + eb[cc][dh * 3 + 0]));
                if (cc) { s1 += e; o1 += e * vd0; } else { s0 += e; o0 += e * vd0; }
                e = exp2v4(q4 * (kd1 + eb[cc][dh * 3 + 1]));
                if (cc) { s1 += e; o1 += e * vd1; } else { s0 += e; o0 += e * vd1; }
                e = exp2v4(q4 * (kd2 + eb[cc][dh * 3 + 2]));
                if (cc) { s1 += e; o1 += e * vd2; } else { s0 += e; o0 += e * vd2; }
            }
        }

        // normalize + store (dwordx4 per channel)
        v4f r0, r1;
        #pragma unroll
        for (int px = 0; px < 4; px++) {
            r0[px] = o0[px] * __builtin_amdgcn_rcpf(s0[px]);
            r1[px] = o1[px] * __builtin_amdgcn_rcpf(s1[px]);
        }
        *reinterpret_cast<v4f*>(out + (size_t)(bg * 8 + c0 + 0) * HW + ibase) = r0;
        *reinterpret_cast<v4f*>(out + (size_t)(bg * 8 + c0 + 1) * HW + ibase) = r1;
    }
}

extern "C" void kernel_launch(void* const* d_in, const int* in_sizes, int n_in,
                              void* d_out, int out_size, void* d_ws, size_t ws_size,
                              hipStream_t stream) {
    const float* x    = (const float*)d_in[0];
    const float* Wq   = (const float*)d_in[1];
    const float* Wk   = (const float*)d_in[2];
    const float* Wv   = (const float*)d_in[3];
    const float* h_e  = (const float*)d_in[4];
    const float* w_e  = (const float*)d_in[5];
    float* out = (float*)d_out;

    dim3 grid(8 * 8 * 16);   // (b,g) x 4x4 tiles = 1024 blocks
    dim3 block(256);
    sab_fused<<<grid, block, 0, stream>>>(x, Wq, Wk, Wv, h_e, w_e, out);
}

// Round 11
// 27.916 us; speedup vs baseline: 2.6067x; 1.1144x over previous
//
#include <hip/hip_runtime.h>

// Stand-alone self-attention block, fully fused.
// x:(8,64,128,128) f32 -> out same shape. G=8, Cg=8, 3x3 window, pad 1.
//
// R11 = R8 (32x32 tile x 2-ch chunk, 4 px/thread, 4096 blocks, SGPR
// weights, b128 LDS reads, streaming no-max exp2 softmax) with:
//  - SCALAR attention math: same VALU issue count as pk version (the pk
//    variant spent its savings on v_mov window builds) but far lower
//    register pressure (no kd/vd temporaries)
//  - gentle __launch_bounds__(256,5): VGPR cap ~102 -> 5 waves/SIMD
//    (+25% occupancy). NOT (256,8), which twice collapsed the allocator
//    to 32 VGPR + scratch spill (R6/R9).
// Tripwire: WRITE_SIZE > 40 MB means scratch spill -> revert bounds.

typedef float v2f __attribute__((ext_vector_type(2)));
typedef float v4f __attribute__((ext_vector_type(4)));

#define HH 128
#define WW 128
#define HW (HH * WW)
#define PT 34          // padded tile extent (32 + halo)
#define PTS 38         // row stride in float2 (34 + 4 pad)
#define LOG2E 1.44269504088896f

__device__ __forceinline__ float sload(float v) {
    // force block-uniform value into an SGPR
    return __uint_as_float(__builtin_amdgcn_readfirstlane(__float_as_uint(v)));
}

__global__ __launch_bounds__(256, 5) void sab_fused(
    const float* __restrict__ x,
    const float* __restrict__ Wq,
    const float* __restrict__ Wk,
    const float* __restrict__ Wv,
    const float* __restrict__ h_emb,
    const float* __restrict__ w_emb,
    float* __restrict__ out)
{
    __shared__ v2f kv[2][PT][PTS];      // [cc][row][col] {k,v}  (20.7 KB)

    const int bid0 = blockIdx.x;
    const int work = (bid0 & 7) * 512 + (bid0 >> 3);   // bijective XCD swizzle
    const int c0   = (work & 3) << 1;          // channel chunk {0,2,4,6}
    const int tile = (work >> 2) & 15;         // 4x4 tiles of 32x32
    const int bg   = work >> 6;                // b*8 + g
    const int g    = bg & 7;
    const int h0   = (tile >> 2) << 5;
    const int w0   = (tile & 3) << 5;
    const int tid  = threadIdx.x;
    const int ty   = tid >> 3;                 // 0..31
    const int x0   = (tid & 7) << 2;           // 0,4,..,28

    // ---- weights + emb -> SGPRs (readfirstlane-forced) ----
    float wk[2][8], wv[2][8], wq[2][8], eb[2][9];
    #pragma unroll
    for (int cc = 0; cc < 2; cc++) {
        const int c = c0 + cc;
        #pragma unroll
        for (int i = 0; i < 8; i++) {
            wk[cc][i] = sload(Wk[g * 64 + c * 8 + i]);
            wv[cc][i] = sload(Wv[g * 64 + c * 8 + i]);
            wq[cc][i] = sload(Wq[g * 64 + c * 8 + i]);
        }
        #pragma unroll
        for (int p = 0; p < 9; p++) {
            // channels 0-3: h_emb (ki = p/3); 4-7: w_emb (kj = p%3)
            eb[cc][p] = sload((c < 4) ? h_emb[(g * 4 + c) * 3 + p / 3]
                                      : w_emb[(g * 4 + c - 4) * 3 + p % 3]);
        }
    }

    const float* xb = x + (size_t)bg * 8 * HW;
    const int ibase = (h0 + ty) * WW + (w0 + x0);

    // ---- interior x: 4 px, 8 channels (dwordx4) ----
    v4f xi[8];
    #pragma unroll
    for (int i = 0; i < 8; i++)
        xi[i] = *reinterpret_cast<const v4f*>(xb + i * HW + ibase);

    // ---- conv (packed): k,v -> LDS, q -> regs ----
    v4f kk0 = 0.f, vv0 = 0.f, qq0 = 0.f, kk1 = 0.f, vv1 = 0.f, qq1 = 0.f;
    #pragma unroll
    for (int i = 0; i < 8; i++) {
        const v4f xv = xi[i];
        kk0 += wk[0][i] * xv;  vv0 += wv[0][i] * xv;  qq0 += wq[0][i] * xv;
        kk1 += wk[1][i] * xv;  vv1 += wv[1][i] * xv;  qq1 += wq[1][i] * xv;
    }
    #pragma unroll
    for (int px = 0; px < 4; px++) {
        kv[0][ty + 1][x0 + 1 + px] = (v2f){kk0[px], vv0[px]};
        kv[1][ty + 1][x0 + 1 + px] = (v2f){kk1[px], vv1[px]};
    }
    float q[2][4];
    #pragma unroll
    for (int px = 0; px < 4; px++) {
        q[0][px] = qq0[px] * LOG2E;
        q[1][px] = qq1[px] * LOG2E;
    }

    // ---- halo: 132 perimeter px on threads 0..131 (transient state) ----
    if (tid < 132) {
        int hpy, hpx;
        if (tid < 34)       { hpy = 0;        hpx = tid; }
        else if (tid < 68)  { hpy = 33;       hpx = tid - 34; }
        else if (tid < 100) { hpy = tid - 67; hpx = 0; }     // rows 1..32
        else                { hpy = tid - 99; hpx = 33; }
        const int gh = h0 + hpy - 1, gw = w0 + hpx - 1;
        const bool ok = (gh >= 0) & (gh < HH) & (gw >= 0) & (gw < WW);
        const int base = gh * WW + gw;
        float hk0 = 0.f, hv0 = 0.f, hk1 = 0.f, hv1 = 0.f;
        #pragma unroll
        for (int i = 0; i < 8; i++) {
            const float xv = ok ? xb[i * HW + base] : 0.0f;
            hk0 = fmaf(wk[0][i], xv, hk0);
            hv0 = fmaf(wv[0][i], xv, hv0);
            hk1 = fmaf(wk[1][i], xv, hk1);
            hv1 = fmaf(wv[1][i], xv, hv1);
        }
        kv[0][hpy][hpx] = (v2f){hk0, hv0};
        kv[1][hpy][hpx] = (v2f){hk1, hv1};
    }
    __syncthreads();

    // ---- attention: scalar streaming softmax (no vector rebuilds) ----
    float s[2][4] = {{0.f,0.f,0.f,0.f},{0.f,0.f,0.f,0.f}};
    float o[2][4] = {{0.f,0.f,0.f,0.f},{0.f,0.f,0.f,0.f}};
    #pragma unroll
    for (int dh = 0; dh < 3; dh++) {
        #pragma unroll
        for (int cc = 0; cc < 2; cc++) {
            const v2f* row = &kv[cc][ty + dh][x0];
            const v4f a  = *reinterpret_cast<const v4f*>(row);      // k0 v0 k1 v1
            const v4f bq = *reinterpret_cast<const v4f*>(row + 2);  // k2 v2 k3 v3
            const v4f cq = *reinterpret_cast<const v4f*>(row + 4);  // k4 v4 k5 v5
            const float kw[6] = {a.x, a.z, bq.x, bq.z, cq.x, cq.z};
            const float vw[6] = {a.y, a.w, bq.y, bq.w, cq.y, cq.w};
            #pragma unroll
            for (int px = 0; px < 4; px++) {
                const float ql = q[cc][px];
                #pragma unroll
                for (int dw = 0; dw < 3; dw++) {
                    const float e = __builtin_amdgcn_exp2f(
                        ql * (kw[px + dw] + eb[cc][dh * 3 + dw]));
                    s[cc][px] += e;
                    o[cc][px] = fmaf(e, vw[px + dw], o[cc][px]);
                }
            }
        }
    }

    // ---- normalize + store (dwordx4 per channel) ----
    v4f r0, r1;
    #pragma unroll
    for (int px = 0; px < 4; px++) {
        r0[px] = o[0][px] * __builtin_amdgcn_rcpf(s[0][px]);
        r1[px] = o[1][px] * __builtin_amdgcn_rcpf(s[1][px]);
    }
    *reinterpret_cast<v4f*>(out + (size_t)(bg * 8 + c0 + 0) * HW + ibase) = r0;
    *reinterpret_cast<v4f*>(out + (size_t)(bg * 8 + c0 + 1) * HW + ibase) = r1;
}

extern "C" void kernel_launch(void* const* d_in, const int* in_sizes, int n_in,
                              void* d_out, int out_size, void* d_ws, size_t ws_size,
                              hipStream_t stream) {
    const float* x    = (const float*)d_in[0];
    const float* Wq   = (const float*)d_in[1];
    const float* Wk   = (const float*)d_in[2];
    const float* Wv   = (const float*)d_in[3];
    const float* h_e  = (const float*)d_in[4];
    const float* w_e  = (const float*)d_in[5];
    float* out = (float*)d_out;

    dim3 grid(8 * 8 * 16 * 4);   // (b,g) x 4x4 tiles x 4 channel-chunks
    dim3 block(256);
    sab_fused<<<grid, block, 0, stream>>>(x, Wq, Wk, Wv, h_e, w_e, out);
}